// Round 2
// baseline (380.349 us; speedup 1.0000x reference)
//
#include <hip/hip_runtime.h>
#include <cstdint>
#include <cmath>

typedef _Float16 half8 __attribute__((ext_vector_type(8)));
typedef unsigned short ushort8 __attribute__((ext_vector_type(8)));
typedef float floatx4 __attribute__((ext_vector_type(4)));

__device__ __forceinline__ unsigned short f2h(float f) {
    union { _Float16 h; unsigned short u; } cv;
    cv.h = (_Float16)f;
    return cv.u;
}

// ---------------- cast x fp32 -> fp16 ----------------
__global__ void cast_x_kernel(const float* __restrict__ x, unsigned short* __restrict__ xh, int n8) {
    int idx = blockIdx.x * blockDim.x + threadIdx.x;
    if (idx >= n8) return;
    const float4* p = (const float4*)x;
    float4 a = p[idx * 2], b = p[idx * 2 + 1];
    ushort8 o;
    o[0] = f2h(a.x); o[1] = f2h(a.y); o[2] = f2h(a.z); o[3] = f2h(a.w);
    o[4] = f2h(b.x); o[5] = f2h(b.y); o[6] = f2h(b.z); o[7] = f2h(b.w);
    *(ushort8*)(xh + (size_t)idx * 8) = o;
}

// ---------------- transpose + cast: in[R][C] fp32 -> out[C][R] fp16 ----------------
__global__ void transpose_cast_kernel(const float* __restrict__ in, unsigned short* __restrict__ out,
                                      int R, int C) {
    __shared__ float tile[32][33];
    int bx = blockIdx.x * 32;  // C block
    int by = blockIdx.y * 32;  // R block
    int x = threadIdx.x, y0 = threadIdx.y;
    #pragma unroll
    for (int k = 0; k < 4; k++) {
        int y = y0 + k * 8;
        tile[y][x] = in[(size_t)(by + y) * C + bx + x];
    }
    __syncthreads();
    #pragma unroll
    for (int k = 0; k < 4; k++) {
        int y = y0 + k * 8;
        out[(size_t)(bx + y) * R + by + x] = f2h(tile[x][y]);
    }
}

// ---------------- 128x128 GEMM: C[M][N] = A[M][K] fp16 * Bt[N][K] fp16 ----------------
// MODE 0: q epilogue (scale by 0.125*log2e, store [b,h,i,d] fp16)
// MODE 2: fp32 out + bias
template<int MODE>
__global__ __launch_bounds__(256) void gemm128_kernel(
    const unsigned short* __restrict__ A, const unsigned short* __restrict__ Bt,
    int K,
    unsigned short* __restrict__ oh, float* __restrict__ of,
    const float* __restrict__ bias)
{
    __shared__ __align__(16) unsigned short As[128 * 40];
    __shared__ __align__(16) unsigned short Bs[128 * 40];
    int t = threadIdx.x;
    int w = t >> 6, lane = t & 63, g = lane >> 4, il = lane & 15;
    int wm = w >> 1, wn = w & 1;
    int m0 = blockIdx.y * 128, n0 = blockIdx.x * 128;
    int sr = t >> 1, sc = (t & 1) * 16;
    floatx4 acc[4][4] = {};
    const unsigned short* Ap = A + (size_t)(m0 + sr) * K + sc;
    const unsigned short* Bp = Bt + (size_t)(n0 + sr) * K + sc;
    for (int k0 = 0; k0 < K; k0 += 32) {
        ushort8 av0 = *(const ushort8*)(Ap + k0);
        ushort8 av1 = *(const ushort8*)(Ap + k0 + 8);
        ushort8 bv0 = *(const ushort8*)(Bp + k0);
        ushort8 bv1 = *(const ushort8*)(Bp + k0 + 8);
        __syncthreads();
        *(ushort8*)&As[sr * 40 + sc]     = av0;
        *(ushort8*)&As[sr * 40 + sc + 8] = av1;
        *(ushort8*)&Bs[sr * 40 + sc]     = bv0;
        *(ushort8*)&Bs[sr * 40 + sc + 8] = bv1;
        __syncthreads();
        half8 af[4], bf[4];
        #pragma unroll
        for (int mt = 0; mt < 4; mt++) af[mt] = *(const half8*)&As[(wm * 64 + mt * 16 + il) * 40 + g * 8];
        #pragma unroll
        for (int nt = 0; nt < 4; nt++) bf[nt] = *(const half8*)&Bs[(wn * 64 + nt * 16 + il) * 40 + g * 8];
        #pragma unroll
        for (int mt = 0; mt < 4; mt++)
            #pragma unroll
            for (int nt = 0; nt < 4; nt++)
                acc[mt][nt] = __builtin_amdgcn_mfma_f32_16x16x32_f16(af[mt], bf[nt], acc[mt][nt], 0, 0, 0);
    }
    #pragma unroll
    for (int mt = 0; mt < 4; mt++) {
        #pragma unroll
        for (int nt = 0; nt < 4; nt++) {
            #pragma unroll
            for (int r = 0; r < 4; r++) {
                int row = m0 + wm * 64 + mt * 16 + 4 * g + r;
                int col = n0 + wn * 64 + nt * 16 + il;
                float v = acc[mt][nt][r];
                if (MODE == 0) {
                    // pre-scaled into exp2 domain: 0.125 * log2(e)
                    int b = row >> 11, i = row & 2047, h = col >> 6, d = col & 63;
                    oh[(size_t)((b * 16 + h) * 2048 + i) * 64 + d] = f2h(v * 0.18033688011112042f);
                } else {
                    of[(size_t)row * 1024 + col] = v + bias[col];
                }
            }
        }
    }
}

// ---------------- 64x64 GEMM for kv projection (N=128), epilogue splits k/v, v transposed ----------------
__global__ __launch_bounds__(256) void gemm64_kv_kernel(
    const unsigned short* __restrict__ A, const unsigned short* __restrict__ Bt,
    unsigned short* __restrict__ kh, unsigned short* __restrict__ vt)
{
    __shared__ __align__(16) unsigned short As[64 * 40];
    __shared__ __align__(16) unsigned short Bs[64 * 40];
    const int K = 1024;
    int t = threadIdx.x;
    int w = t >> 6, lane = t & 63, g = lane >> 4, il = lane & 15;
    int m0 = blockIdx.y * 64, n0 = blockIdx.x * 64;
    int ar = t >> 2, ac = (t & 3) * 8;
    floatx4 acc[4] = {{0,0,0,0},{0,0,0,0},{0,0,0,0},{0,0,0,0}};
    const unsigned short* Ap = A + (size_t)(m0 + ar) * K + ac;
    const unsigned short* Bp = Bt + (size_t)(n0 + ar) * K + ac;
    for (int k0 = 0; k0 < K; k0 += 32) {
        ushort8 av = *(const ushort8*)(Ap + k0);
        ushort8 bv = *(const ushort8*)(Bp + k0);
        __syncthreads();
        *(ushort8*)&As[ar * 40 + ac] = av;
        *(ushort8*)&Bs[ar * 40 + ac] = bv;
        __syncthreads();
        half8 af = *(const half8*)&As[(w * 16 + il) * 40 + g * 8];
        #pragma unroll
        for (int nt = 0; nt < 4; nt++) {
            half8 bf = *(const half8*)&Bs[(nt * 16 + il) * 40 + g * 8];
            acc[nt] = __builtin_amdgcn_mfma_f32_16x16x32_f16(af, bf, acc[nt], 0, 0, 0);
        }
    }
    #pragma unroll
    for (int nt = 0; nt < 4; nt++) {
        #pragma unroll
        for (int r = 0; r < 4; r++) {
            int row = m0 + w * 16 + 4 * g + r;  // b*2048 + j
            int col = n0 + nt * 16 + il;
            float v = acc[nt][r];
            if (col < 64) {
                kh[(size_t)row * 64 + col] = f2h(v);
            } else {
                int b = row >> 11, j = row & 2047;
                vt[(size_t)((b << 6) + (col - 64)) * 2048 + j] = f2h(v);
            }
        }
    }
}

// ---------------- flash attention, barrier-free inner loop ----------------
// Grid: (32 i-tiles reversed, 32 b*h). Block 256 = 4 waves; wave w owns rows iw..iw+15.
// S^T = K.Q^T (n=i so softmax rows are per-lane). V read directly from global V^T.
__global__ __launch_bounds__(256) void attn_kernel(
    const unsigned short* __restrict__ qh, const unsigned short* __restrict__ kh,
    const unsigned short* __restrict__ vt, const float* __restrict__ rel_emb,
    unsigned short* __restrict__ ob)
{
    __shared__ float bias_tab[2048];
    __shared__ __align__(16) unsigned short Pl[64 * 72];  // per-wave-private P rows, stride 72
    int bx = 31 - blockIdx.x;  // longest blocks dispatch first
    int bh = blockIdx.y;
    int b = bh >> 4, h = bh & 15;
    int t = threadIdx.x;
    int w = t >> 6, lane = t & 63, g = lane >> 4, il = lane & 15;

    // bias table over delta in [0, (bx+1)*64), exp2 domain (x 8*log2e)
    int nd = (bx + 1) * 64;
    for (int dlt = t; dlt < nd; dlt += 256) {
        int bucket;
        if (dlt < 16) bucket = dlt;
        else {
            float lg = logf((float)dlt * 0.0625f) / 2.0794415416798357f;
            int vv = 16 + (int)(lg * 16.0f);
            bucket = vv < 31 ? vv : 31;
        }
        bias_tab[dlt] = rel_emb[bucket * 16 + h] * 11.541560327111708f;
    }
    __syncthreads();

    int iw = bx * 64 + w * 16;
    int i_glob = iw + il;
    const unsigned short* qrow = qh + (size_t)(bh * 2048 + i_glob) * 64;
    half8 qf0 = *(const half8*)(qrow + g * 8);
    half8 qf1 = *(const half8*)(qrow + 32 + g * 8);
    const unsigned short* kbase = kh + (size_t)b * (2048 * 64);
    const unsigned short* vbase = vt + (size_t)b * (64 * 2048);
    floatx4 O[4] = {{0,0,0,0},{0,0,0,0},{0,0,0,0},{0,0,0,0}};
    float m_run = -1e30f, l_run = 0.0f;
    int prow = (w * 16 + il) * 72;

    for (int c = 0; c <= bx; c++) {
        int j0 = c * 64;
        // S^T: 4 j-subtiles of 16, K over d=64 in two MFMAs
        floatx4 S[4] = {{0,0,0,0},{0,0,0,0},{0,0,0,0},{0,0,0,0}};
        #pragma unroll
        for (int jt = 0; jt < 4; jt++) {
            const unsigned short* kr = kbase + (size_t)(j0 + jt * 16 + il) * 64;
            half8 k0 = *(const half8*)(kr + g * 8);
            half8 k1 = *(const half8*)(kr + 32 + g * 8);
            S[jt] = __builtin_amdgcn_mfma_f32_16x16x32_f16(k0, qf0, S[jt], 0, 0, 0);
            S[jt] = __builtin_amdgcn_mfma_f32_16x16x32_f16(k1, qf1, S[jt], 0, 0, 0);
        }
        // bias (+ mask only on diagonal chunk); lane: i = i_glob, j = j0 + jt*16 + 4g + r
        float s[16];
        if (c < bx) {
            #pragma unroll
            for (int jt = 0; jt < 4; jt++)
                #pragma unroll
                for (int r = 0; r < 4; r++)
                    s[jt * 4 + r] = S[jt][r] + bias_tab[i_glob - (j0 + jt * 16 + 4 * g + r)];
        } else {
            #pragma unroll
            for (int jt = 0; jt < 4; jt++) {
                #pragma unroll
                for (int r = 0; r < 4; r++) {
                    int delta = i_glob - (j0 + jt * 16 + 4 * g + r);
                    int di = delta > 0 ? delta : 0;
                    s[jt * 4 + r] = (delta >= 0) ? (S[jt][r] + bias_tab[di]) : -1e30f;
                }
            }
        }
        // online softmax (exp2 domain); row stats per (lane&15), reduce over 4 g-groups
        float mx = s[0];
        #pragma unroll
        for (int q2 = 1; q2 < 16; q2++) mx = fmaxf(mx, s[q2]);
        mx = fmaxf(mx, __shfl_xor(mx, 16));
        mx = fmaxf(mx, __shfl_xor(mx, 32));
        float m_new = fmaxf(m_run, mx);
        float alpha = __builtin_amdgcn_exp2f(m_run - m_new);
        float p[16], psum = 0.0f;
        #pragma unroll
        for (int q2 = 0; q2 < 16; q2++) { p[q2] = __builtin_amdgcn_exp2f(s[q2] - m_new); psum += p[q2]; }
        psum += __shfl_xor(psum, 16);
        psum += __shfl_xor(psum, 32);
        l_run = l_run * alpha + psum;
        m_run = m_new;
        float arow[4];
        #pragma unroll
        for (int r = 0; r < 4; r++) arow[r] = __shfl(alpha, 4 * g + r);
        #pragma unroll
        for (int dt = 0; dt < 4; dt++)
            #pragma unroll
            for (int r = 0; r < 4; r++) O[dt][r] *= arow[r];
        // pack P to fp16, wave-private LDS rows (no barrier needed)
        #pragma unroll
        for (int jt = 0; jt < 4; jt++) {
            uint2 u;
            u.x = (unsigned int)f2h(p[jt * 4 + 0]) | ((unsigned int)f2h(p[jt * 4 + 1]) << 16);
            u.y = (unsigned int)f2h(p[jt * 4 + 2]) | ((unsigned int)f2h(p[jt * 4 + 3]) << 16);
            *(uint2*)&Pl[prow + jt * 16 + 4 * g] = u;
        }
        // PV: A = P[i][j] from LDS, B = V[j][d] as b128 from global V^T (L2-resident)
        #pragma unroll
        for (int ks = 0; ks < 2; ks++) {
            half8 pf = *(const half8*)&Pl[prow + ks * 32 + g * 8];
            #pragma unroll
            for (int dt = 0; dt < 4; dt++) {
                half8 vf = *(const half8*)(vbase + (size_t)(dt * 16 + il) * 2048 + j0 + ks * 32 + g * 8);
                O[dt] = __builtin_amdgcn_mfma_f32_16x16x32_f16(pf, vf, O[dt], 0, 0, 0);
            }
        }
    }
    // epilogue: normalize, store [b*2048+i][h*64+d] fp16
    float inv[4];
    #pragma unroll
    for (int r = 0; r < 4; r++) inv[r] = 1.0f / __shfl(l_run, 4 * g + r);
    #pragma unroll
    for (int dt = 0; dt < 4; dt++) {
        #pragma unroll
        for (int r = 0; r < 4; r++) {
            int i = iw + 4 * g + r;
            int d = dt * 16 + il;
            ob[(size_t)(b * 2048 + i) * 1024 + h * 64 + d] = f2h(O[dt][r] * inv[r]);
        }
    }
}

extern "C" void kernel_launch(void* const* d_in, const int* in_sizes, int n_in,
                              void* d_out, int out_size, void* d_ws, size_t ws_size,
                              hipStream_t stream) {
    const float* x    = (const float*)d_in[0];
    const float* Wq   = (const float*)d_in[1];
    const float* Wkv  = (const float*)d_in[2];
    const float* Wout = (const float*)d_in[3];
    const float* bout = (const float*)d_in[4];
    const float* rel  = (const float*)d_in[5];
    float* out = (float*)d_out;

    unsigned short* ws   = (unsigned short*)d_ws;
    unsigned short* xh   = ws;                    // 4096x1024 fp16 (x), later reused as attn_out
    unsigned short* qh   = xh + 4194304;          // [b,h,i,d] fp16, pre-scaled (exp2 domain)
    unsigned short* kh   = qh + 4194304;          // [b*2048+j][d]
    unsigned short* vt   = kh + 262144;           // [b][d][j]  (V transposed)
    unsigned short* Wqt  = vt + 262144;           // [1024][1024]
    unsigned short* Wkvt = Wqt + 1048576;         // [128][1024]
    unsigned short* Wot  = Wkvt + 131072;         // [1024][1024]
    unsigned short* ob   = xh;                    // alias: x dead after projections

    cast_x_kernel<<<2048, 256, 0, stream>>>(x, xh, 524288);
    transpose_cast_kernel<<<dim3(32, 32), dim3(32, 8), 0, stream>>>(Wq,   Wqt,  1024, 1024);
    transpose_cast_kernel<<<dim3(4, 32),  dim3(32, 8), 0, stream>>>(Wkv,  Wkvt, 1024, 128);
    transpose_cast_kernel<<<dim3(32, 32), dim3(32, 8), 0, stream>>>(Wout, Wot,  1024, 1024);
    gemm128_kernel<0><<<dim3(8, 32), 256, 0, stream>>>(xh, Wqt, 1024, qh, nullptr, nullptr);
    gemm64_kv_kernel<<<dim3(2, 64), 256, 0, stream>>>(xh, Wkvt, kh, vt);
    attn_kernel<<<dim3(32, 32), 256, 0, stream>>>(qh, kh, vt, rel, ob);
    gemm128_kernel<2><<<dim3(8, 32), 256, 0, stream>>>(ob, Wot, 1024, nullptr, out, bout);
}

// Round 3
// 233.371 us; speedup vs baseline: 1.6298x; 1.6298x over previous
//
#include <hip/hip_runtime.h>
#include <cstdint>
#include <cmath>

typedef _Float16 half8 __attribute__((ext_vector_type(8)));
typedef unsigned short ushort8 __attribute__((ext_vector_type(8)));
typedef float floatx4 __attribute__((ext_vector_type(4)));

#define VT_STRIDE 2080  // 2048 + 32: breaks 4KB L2 set aliasing on V^T rows

__device__ __forceinline__ unsigned short f2h(float f) {
    union { _Float16 h; unsigned short u; } cv;
    cv.h = (_Float16)f;
    return cv.u;
}

// ---------------- cast x fp32 -> fp16 ----------------
__global__ void cast_x_kernel(const float* __restrict__ x, unsigned short* __restrict__ xh, int n8) {
    int idx = blockIdx.x * blockDim.x + threadIdx.x;
    if (idx >= n8) return;
    const float4* p = (const float4*)x;
    float4 a = p[idx * 2], b = p[idx * 2 + 1];
    ushort8 o;
    o[0] = f2h(a.x); o[1] = f2h(a.y); o[2] = f2h(a.z); o[3] = f2h(a.w);
    o[4] = f2h(b.x); o[5] = f2h(b.y); o[6] = f2h(b.z); o[7] = f2h(b.w);
    *(ushort8*)(xh + (size_t)idx * 8) = o;
}

// ---------------- fused transpose+cast of Wq, Wkv, Wout (R=1024 rows each) ----------------
// Wq -> Wqkvt rows 0..1023, Wkv -> Wqkvt rows 1024..1151, Wout -> Wot
__global__ void transpose_fused_kernel(const float* __restrict__ Wq, const float* __restrict__ Wkv,
                                       const float* __restrict__ Wout,
                                       unsigned short* __restrict__ Wqkvt, unsigned short* __restrict__ Wot) {
    __shared__ float tile[32][33];
    int bxi = blockIdx.x;
    const float* in; unsigned short* out; int C; int cb;
    if (bxi < 32)      { in = Wq;   out = Wqkvt;                 C = 1024; cb = bxi; }
    else if (bxi < 36) { in = Wkv;  out = Wqkvt + 1024 * 1024;   C = 128;  cb = bxi - 32; }
    else               { in = Wout; out = Wot;                   C = 1024; cb = bxi - 36; }
    int bx = cb * 32, by = blockIdx.y * 32;
    int x = threadIdx.x, y0 = threadIdx.y;
    #pragma unroll
    for (int k = 0; k < 4; k++) {
        int y = y0 + k * 8;
        tile[y][x] = in[(size_t)(by + y) * C + bx + x];
    }
    __syncthreads();
    #pragma unroll
    for (int k = 0; k < 4; k++) {
        int y = y0 + k * 8;
        out[(size_t)(bx + y) * 1024 + by + x] = f2h(tile[x][y]);
    }
}

// ---------------- GEMM 64M x 128N x 32K: C = A[M][K] * Bt[N][K], fp16 ----------------
// MODE 0: fused q/k/v epilogue (col<1024 q -> [b,h,i,d] scaled; <1088 k; else v -> V^T padded)
// MODE 2: fp32 out + bias
template<int MODE>
__global__ __launch_bounds__(256) void gemm_mn(
    const unsigned short* __restrict__ A, const unsigned short* __restrict__ Bt,
    unsigned short* __restrict__ oq, unsigned short* __restrict__ ok,
    unsigned short* __restrict__ ov, float* __restrict__ of,
    const float* __restrict__ bias)
{
    __shared__ __align__(16) unsigned short As[64 * 40];
    __shared__ __align__(16) unsigned short Bs[128 * 40];
    const int K = 1024;
    int t = threadIdx.x;
    int w = t >> 6, lane = t & 63, g = lane >> 4, il = lane & 15;
    int m0 = blockIdx.y * 64, n0 = blockIdx.x * 128;
    int ar = t >> 2, ac = (t & 3) * 8;     // A: 64 rows x 32, 1 vec8/thread
    int br = t >> 1, bc = (t & 1) * 16;    // B: 128 rows x 32, 2 vec8/thread
    floatx4 acc[8] = {};
    const unsigned short* Ap = A + (size_t)(m0 + ar) * K + ac;
    const unsigned short* Bp = Bt + (size_t)(n0 + br) * K + bc;
    for (int k0 = 0; k0 < K; k0 += 32) {
        ushort8 av  = *(const ushort8*)(Ap + k0);
        ushort8 bv0 = *(const ushort8*)(Bp + k0);
        ushort8 bv1 = *(const ushort8*)(Bp + k0 + 8);
        __syncthreads();
        *(ushort8*)&As[ar * 40 + ac] = av;
        *(ushort8*)&Bs[br * 40 + bc] = bv0;
        *(ushort8*)&Bs[br * 40 + bc + 8] = bv1;
        __syncthreads();
        half8 af = *(const half8*)&As[(w * 16 + il) * 40 + g * 8];
        #pragma unroll
        for (int nt = 0; nt < 8; nt++) {
            half8 bf = *(const half8*)&Bs[(nt * 16 + il) * 40 + g * 8];
            acc[nt] = __builtin_amdgcn_mfma_f32_16x16x32_f16(af, bf, acc[nt], 0, 0, 0);
        }
    }
    #pragma unroll
    for (int nt = 0; nt < 8; nt++) {
        #pragma unroll
        for (int r = 0; r < 4; r++) {
            int row = m0 + w * 16 + 4 * g + r;     // b*2048 + i
            int col = n0 + nt * 16 + il;
            float v = acc[nt][r];
            if (MODE == 0) {
                if (col < 1024) {
                    int b = row >> 11, i = row & 2047, h = col >> 6, d = col & 63;
                    // pre-scale into exp2 domain: 0.125 * log2(e)
                    oq[(size_t)((b * 16 + h) * 2048 + i) * 64 + d] = f2h(v * 0.18033688011112042f);
                } else if (col < 1088) {
                    ok[(size_t)row * 64 + (col - 1024)] = f2h(v);
                } else {
                    int b = row >> 11, j = row & 2047;
                    ov[(size_t)((b << 6) + (col - 1088)) * VT_STRIDE + j] = f2h(v);
                }
            } else {
                of[(size_t)row * 1024 + col] = v + bias[col];
            }
        }
    }
}

// ---------------- flash attention, paired tiles + software-pipelined loads ----------------
// Grid: (16 tile-pairs, 32 b*h). Block 256 = 4 waves; wave w owns 16 Q rows.
// Each block does tiles {31-p, p}: exactly 33 chunks -> perfect balance.
// S^T = K.Q^T (softmax rows per-lane). V from padded global V^T; K(c+1)/V(c) prefetched.
__global__ __launch_bounds__(256) void attn_kernel(
    const unsigned short* __restrict__ qh, const unsigned short* __restrict__ kh,
    const unsigned short* __restrict__ vt, const float* __restrict__ rel_emb,
    unsigned short* __restrict__ ob)
{
    __shared__ float bias_tab[256];
    __shared__ __align__(16) unsigned short Pl[64 * 72];  // wave-private P rows, stride 72
    int pr = blockIdx.x;
    int bh = blockIdx.y;
    int b = bh >> 4, h = bh & 15;
    int t = threadIdx.x;
    int w = t >> 6, lane = t & 63, g = lane >> 4, il = lane & 15;

    // bias table only needed for delta < 256 (nearer chunks); bucket saturates at 31 for delta>=113
    {
        int dlt = t;
        int bucket;
        if (dlt < 16) bucket = dlt;
        else {
            float lg = logf((float)dlt * 0.0625f) / 2.0794415416798357f;
            int vv = 16 + (int)(lg * 16.0f);
            bucket = vv < 31 ? vv : 31;
        }
        bias_tab[dlt] = rel_emb[bucket * 16 + h] * 11.541560327111708f;
    }
    float cb31 = rel_emb[31 * 16 + h] * 11.541560327111708f;
    __syncthreads();

    const unsigned short* kbase = kh + (size_t)b * (2048 * 64);
    const unsigned short* vbase = vt + (size_t)b * (64 * VT_STRIDE);
    int prow = (w * 16 + il) * 72;

    #pragma unroll
    for (int tt = 0; tt < 2; tt++) {
        int bx = (tt == 0) ? (31 - pr) : pr;
        int iw = bx * 64 + w * 16;
        int i_glob = iw + il;
        const unsigned short* qrow = qh + (size_t)(bh * 2048 + i_glob) * 64;
        half8 qf0 = *(const half8*)(qrow + g * 8);
        half8 qf1 = *(const half8*)(qrow + 32 + g * 8);
        floatx4 O[4] = {};
        float m_run = -1e30f, l_run = 0.0f;

        // prefetch K chunk 0
        half8 kA0[4], kA1[4];
        #pragma unroll
        for (int jt = 0; jt < 4; jt++) {
            const unsigned short* kr = kbase + (size_t)(jt * 16 + il) * 64;
            kA0[jt] = *(const half8*)(kr + g * 8);
            kA1[jt] = *(const half8*)(kr + 32 + g * 8);
        }

        for (int c = 0; c <= bx; c++) {
            int j0 = c * 64;
            // issue V loads for this chunk early (consumed after softmax)
            half8 vf[8];
            #pragma unroll
            for (int ks = 0; ks < 2; ks++)
                #pragma unroll
                for (int dt = 0; dt < 4; dt++)
                    vf[ks * 4 + dt] = *(const half8*)(vbase + (size_t)(dt * 16 + il) * VT_STRIDE + j0 + ks * 32 + g * 8);
            // S^T from prefetched K
            floatx4 S[4] = {};
            #pragma unroll
            for (int jt = 0; jt < 4; jt++) {
                S[jt] = __builtin_amdgcn_mfma_f32_16x16x32_f16(kA0[jt], qf0, S[jt], 0, 0, 0);
                S[jt] = __builtin_amdgcn_mfma_f32_16x16x32_f16(kA1[jt], qf1, S[jt], 0, 0, 0);
            }
            // prefetch K for chunk c+1
            half8 kB0[4], kB1[4];
            if (c < bx) {
                #pragma unroll
                for (int jt = 0; jt < 4; jt++) {
                    const unsigned short* kr = kbase + (size_t)(j0 + 64 + jt * 16 + il) * 64;
                    kB0[jt] = *(const half8*)(kr + g * 8);
                    kB1[jt] = *(const half8*)(kr + 32 + g * 8);
                }
            }
            // bias: constant far from diagonal; table gather near; mask on diagonal chunk
            float s[16];
            if (c + 3 <= bx) {
                #pragma unroll
                for (int q2 = 0; q2 < 16; q2++) s[q2] = S[q2 >> 2][q2 & 3] + cb31;
            } else if (c < bx) {
                #pragma unroll
                for (int jt = 0; jt < 4; jt++)
                    #pragma unroll
                    for (int r = 0; r < 4; r++)
                        s[jt * 4 + r] = S[jt][r] + bias_tab[i_glob - (j0 + jt * 16 + 4 * g + r)];
            } else {
                #pragma unroll
                for (int jt = 0; jt < 4; jt++) {
                    #pragma unroll
                    for (int r = 0; r < 4; r++) {
                        int delta = i_glob - (j0 + jt * 16 + 4 * g + r);
                        int di = delta > 0 ? delta : 0;
                        s[jt * 4 + r] = (delta >= 0) ? (S[jt][r] + bias_tab[di]) : -1e30f;
                    }
                }
            }
            // online softmax in exp2 domain; rows per (lane&15), reduce over g-groups
            float mx = s[0];
            #pragma unroll
            for (int q2 = 1; q2 < 16; q2++) mx = fmaxf(mx, s[q2]);
            mx = fmaxf(mx, __shfl_xor(mx, 16));
            mx = fmaxf(mx, __shfl_xor(mx, 32));
            float m_new = fmaxf(m_run, mx);
            float alpha = __builtin_amdgcn_exp2f(m_run - m_new);
            float p[16], psum = 0.0f;
            #pragma unroll
            for (int q2 = 0; q2 < 16; q2++) { p[q2] = __builtin_amdgcn_exp2f(s[q2] - m_new); psum += p[q2]; }
            psum += __shfl_xor(psum, 16);
            psum += __shfl_xor(psum, 32);
            l_run = l_run * alpha + psum;
            m_run = m_new;
            float arow[4];
            #pragma unroll
            for (int r = 0; r < 4; r++) arow[r] = __shfl(alpha, 4 * g + r);
            #pragma unroll
            for (int dt = 0; dt < 4; dt++)
                #pragma unroll
                for (int r = 0; r < 4; r++) O[dt][r] *= arow[r];
            // pack P fp16 -> wave-private LDS (C-layout -> A-layout transform)
            #pragma unroll
            for (int jt = 0; jt < 4; jt++) {
                uint2 u;
                u.x = (unsigned int)f2h(p[jt * 4 + 0]) | ((unsigned int)f2h(p[jt * 4 + 1]) << 16);
                u.y = (unsigned int)f2h(p[jt * 4 + 2]) | ((unsigned int)f2h(p[jt * 4 + 3]) << 16);
                *(uint2*)&Pl[prow + jt * 16 + 4 * g] = u;
            }
            // PV with prefetched V
            #pragma unroll
            for (int ks = 0; ks < 2; ks++) {
                half8 pf = *(const half8*)&Pl[prow + ks * 32 + g * 8];
                #pragma unroll
                for (int dt = 0; dt < 4; dt++)
                    O[dt] = __builtin_amdgcn_mfma_f32_16x16x32_f16(pf, vf[ks * 4 + dt], O[dt], 0, 0, 0);
            }
            // rotate prefetched K
            if (c < bx) {
                #pragma unroll
                for (int jt = 0; jt < 4; jt++) { kA0[jt] = kB0[jt]; kA1[jt] = kB1[jt]; }
            }
        }
        // epilogue: normalize, store [b*2048+i][h*64+d] fp16
        float inv[4];
        #pragma unroll
        for (int r = 0; r < 4; r++) inv[r] = 1.0f / __shfl(l_run, 4 * g + r);
        #pragma unroll
        for (int dt = 0; dt < 4; dt++) {
            #pragma unroll
            for (int r = 0; r < 4; r++) {
                int i = iw + 4 * g + r;
                int d = dt * 16 + il;
                ob[(size_t)(b * 2048 + i) * 1024 + h * 64 + d] = f2h(O[dt][r] * inv[r]);
            }
        }
    }
}

extern "C" void kernel_launch(void* const* d_in, const int* in_sizes, int n_in,
                              void* d_out, int out_size, void* d_ws, size_t ws_size,
                              hipStream_t stream) {
    const float* x    = (const float*)d_in[0];
    const float* Wq   = (const float*)d_in[1];
    const float* Wkv  = (const float*)d_in[2];
    const float* Wout = (const float*)d_in[3];
    const float* bout = (const float*)d_in[4];
    const float* rel  = (const float*)d_in[5];
    float* out = (float*)d_out;

    unsigned short* ws    = (unsigned short*)d_ws;
    unsigned short* xh    = ws;                      // [4096][1024] fp16 x; reused as attn out
    unsigned short* qh    = xh + 4194304;            // [b,h,i,d] fp16, exp2-domain prescaled
    unsigned short* kh    = qh + 4194304;            // [b*2048+j][64]
    unsigned short* vt    = kh + 262144;             // [b][64][VT_STRIDE] padded V^T
    unsigned short* Wqkvt = vt + 2 * 64 * VT_STRIDE; // [1152][1024]
    unsigned short* Wot   = Wqkvt + 1179648;         // [1024][1024]
    unsigned short* ob    = xh;

    cast_x_kernel<<<2048, 256, 0, stream>>>(x, xh, 524288);
    transpose_fused_kernel<<<dim3(68, 32), dim3(32, 8), 0, stream>>>(Wq, Wkv, Wout, Wqkvt, Wot);
    gemm_mn<0><<<dim3(9, 64), 256, 0, stream>>>(xh, Wqkvt, qh, kh, vt, nullptr, nullptr);
    attn_kernel<<<dim3(16, 32), 256, 0, stream>>>(qh, kh, vt, rel, ob);
    gemm_mn<2><<<dim3(8, 64), 256, 0, stream>>>(ob, Wot, nullptr, nullptr, nullptr, out, bout);
}